// Round 15
// baseline (66.459 us; speedup 1.0000x reference)
//
#include <hip/hip_runtime.h>

#define N_NODES 4096
#define HW 256
#define NODE_ELEMS 4096
#define E_EDGES 16384
#define PITCH 16            // 32B cells; halves swizzled (see sw_off) to avoid 4-way banks
#define TILE_E (18*18*PITCH)
#define CAP 32              // per-node edge bucket capacity (deg ~ Poisson(4))

typedef __attribute__((ext_vector_type(8))) short short8;
typedef __attribute__((ext_vector_type(4))) float f32x4;

// swizzled element offset of the 16B half (c8 = 0 or 8) of cell
__device__ inline int sw_off(int cell, int c8) {
    return (cell << 4) + (c8 ^ ((cell & 4) << 1));
}

__device__ inline unsigned short f2bf(float f) {
    union { float f; unsigned int u; } a; a.f = f;
    unsigned int r = a.u + 0x7fffu + ((a.u >> 16) & 1u);   // RNE
    return (unsigned short)(r >> 16);
}

__device__ inline void acc8(float* aacc, uint4 a, uint4 b) {
    unsigned int wd[8] = { a.x, a.y, a.z, a.w, b.x, b.y, b.z, b.w };
#pragma unroll
    for (int m = 0; m < 8; m++) {
        union { unsigned int u; float f; } lo, hi;
        lo.u = wd[m] << 16;
        hi.u = wd[m] & 0xffff0000u;
        aacc[2 * m]     += lo.f;
        aacc[2 * m + 1] += hi.f;
    }
}

// ---- edge-index dtype hedge (int64 vs int32) ----
__device__ inline bool detect_i64(const int* p) {
    int z = 0;
#pragma unroll
    for (int i = 0; i < 16; i++) z += (p[2 * i + 1] == 0) ? 1 : 0;
    return z == 16;
}
__device__ inline int eidx(const int* p, bool i64, int i) { return i64 ? p[2 * i] : p[i]; }

// ---- w2 repack: w2[co*288 + k], k = partSel*144 + tap*16 + c ----
__device__ inline void w2_repack(int t, const float* Ww, const float* Bw,
                                 unsigned short* w2) {
    for (int i = t; i < 16 * 288; i += 256) {
        int co = i / 288, k = i % 288;
        int p = (k >= 144) ? 1 : 0;
        int kk = k - p * 144;
        int tap = kk >> 4, c = kk & 15;
        const float* srcw = p ? Bw : Ww;
        w2[i] = f2bf(srcw[co * 144 + c * 9 + tap]);
    }
}

// 4 blocks: zero cnt (1024 int4) + block 0 repacks weights.
__global__ __launch_bounds__(256) void zero_w2(
    int* __restrict__ cnt,
    const float* __restrict__ Ww, const float* __restrict__ Bw,
    unsigned short* __restrict__ w2)
{
    int t = blockIdx.x * blockDim.x + threadIdx.x;
    ((int4*)cnt)[t] = make_int4(0, 0, 0, 0);
    if (blockIdx.x == 0) w2_repack(threadIdx.x, Ww, Bw, w2);
}

// 4096 blocks: convert node n (f32 [c][pos] -> bf16 [pos][c]) + bucket 4 edges.
// (r13-proven form; x reads non-temporal — read-once data, keep L2 for xbf.)
__global__ __launch_bounds__(256) void convert_bucket(
    const float* __restrict__ x, const int* __restrict__ ei,
    unsigned short* __restrict__ xbf, int* __restrict__ cnt,
    int* __restrict__ esrc2)
{
    int n = blockIdx.x, t = threadIdx.x;
    if (t < 4) {
        bool i64 = detect_i64(ei);
        int e = n * 4 + t;
        int s = eidx(ei, i64, e);
        int d = eidx(ei, i64, E_EDGES + e);
        int slot = atomicAdd(&cnt[d], 1);
        if (slot < CAP) esrc2[d * CAP + slot] = s;
    }

    const float* xn = x + (size_t)n * NODE_ELEMS;
    union { unsigned int w[4]; uint4 v; } u0, u1;
#pragma unroll
    for (int k2 = 0; k2 < 4; k2++) {
        float a = __builtin_nontemporal_load(&xn[(2 * k2) * HW + t]);
        float b = __builtin_nontemporal_load(&xn[(2 * k2 + 1) * HW + t]);
        u0.w[k2] = (unsigned int)f2bf(a) | ((unsigned int)f2bf(b) << 16);
    }
#pragma unroll
    for (int k2 = 0; k2 < 4; k2++) {
        float a = __builtin_nontemporal_load(&xn[(8 + 2 * k2) * HW + t]);
        float b = __builtin_nontemporal_load(&xn[(9 + 2 * k2) * HW + t]);
        u1.w[k2] = (unsigned int)f2bf(a) | ((unsigned int)f2bf(b) << 16);
    }
    uint4* dst = (uint4*)(xbf + (size_t)n * NODE_ELEMS + t * 16);
    dst[0] = u0.v; dst[1] = u1.v;
}

// Path-B prep: buckets only (no xbf space).
__global__ void bucket_only(const int* __restrict__ ei, int* __restrict__ cnt,
                            int* __restrict__ esrc2) {
    bool i64 = detect_i64(ei);
    int e = blockIdx.x * blockDim.x + threadIdx.x;
    if (e < E_EDGES) {
        int s = eidx(ei, i64, e);
        int d = eidx(ei, i64, E_EDGES + e);
        int slot = atomicAdd(&cnt[d], 1);
        if (slot < CAP) esrc2[d * CAP + slot] = s;
    }
}

// ================= path A: bf16 gather, swizzled LDS, 1 barrier, nt out =================
__global__ __launch_bounds__(256) void fused_bf(
    const unsigned short* __restrict__ xbf,
    const unsigned short* __restrict__ w2,
    const float* __restrict__ Wb, const float* __restrict__ Bb,
    const int* __restrict__ cnt, const int* __restrict__ esrc2,
    float* __restrict__ out)
{
    __shared__ __align__(16) unsigned short xs[TILE_E];
    __shared__ __align__(16) unsigned short as_[TILE_E];

    int n = blockIdx.x;
    int t = threadIdx.x;
    int h = t >> 4, w = t & 15;

    // ---- issue all independent loads up front ----
    int dg = cnt[n];
    const int* sl = esrc2 + n * CAP;
    int4 s03 = *(const int4*)sl;          // unconditional: region always allocated
    int4 s47 = *(const int4*)(sl + 4);
    const uint4* px = (const uint4*)(xbf + (size_t)n * NODE_ELEMS + t * 16);
    uint4 own0 = px[0], own1 = px[1];

    // ---- zero ONLY border cells (interior fully overwritten) ----
    if (t < 136) {
        unsigned short* tile = (t < 68) ? xs : as_;
        int i = (t < 68) ? t : t - 68;
        int r, c;
        if (i < 18)      { r = 0;          c = i; }
        else if (i < 36) { r = 17;         c = i - 18; }
        else if (i < 52) { r = i - 36 + 1; c = 0; }
        else             { r = i - 52 + 1; c = 17; }
        uint4 z = make_uint4(0, 0, 0, 0);
        unsigned short* p = tile + ((r * 18 + c) << 4);
        *(uint4*)p = z; *(uint4*)(p + 8) = z;
    }

    int cell = (h + 1) * 18 + (w + 1);
    // stage own x-tile (swizzled halves)
    *(uint4*)&xs[sw_off(cell, 0)] = own0;
    *(uint4*)&xs[sw_off(cell, 8)] = own1;

    // ---- gather-sum neighbors: guarded quads (uniform branches) ----
    int m = dg < CAP ? dg : CAP;
#define IMG(s) ((const uint4*)(xbf + (size_t)(s) * NODE_ELEMS + t * 16))
    float aacc[16];
#pragma unroll
    for (int k = 0; k < 16; k++) aacc[k] = 0.f;
    {
        uint4 a0, b0, a1, b1, a2, b2, a3, b3;
        if (m > 0) { const uint4* q = IMG(s03.x); a0 = q[0]; b0 = q[1]; }
        if (m > 1) { const uint4* q = IMG(s03.y); a1 = q[0]; b1 = q[1]; }
        if (m > 2) { const uint4* q = IMG(s03.z); a2 = q[0]; b2 = q[1]; }
        if (m > 3) { const uint4* q = IMG(s03.w); a3 = q[0]; b3 = q[1]; }
        if (m > 0) acc8(aacc, a0, b0);
        if (m > 1) acc8(aacc, a1, b1);
        if (m > 2) acc8(aacc, a2, b2);
        if (m > 3) acc8(aacc, a3, b3);
    }
    if (m > 4) {
        uint4 a0, b0, a1, b1, a2, b2, a3, b3;
        { const uint4* q = IMG(s47.x); a0 = q[0]; b0 = q[1]; }
        if (m > 5) { const uint4* q = IMG(s47.y); a1 = q[0]; b1 = q[1]; }
        if (m > 6) { const uint4* q = IMG(s47.z); a2 = q[0]; b2 = q[1]; }
        if (m > 7) { const uint4* q = IMG(s47.w); a3 = q[0]; b3 = q[1]; }
        acc8(aacc, a0, b0);
        if (m > 5) acc8(aacc, a1, b1);
        if (m > 6) acc8(aacc, a2, b2);
        if (m > 7) acc8(aacc, a3, b3);
        for (int j = 8; j < m; j++) { const uint4* q = IMG(sl[j]); acc8(aacc, q[0], q[1]); }
    }
#undef IMG
    float scale = 1.0f / (float)(dg > 1 ? dg : 1);

    {   // stage agg interior (bf16 pack, swizzled halves)
        union { unsigned short us[8]; uint4 v; } pk;
#pragma unroll
        for (int half = 0; half < 2; half++) {
#pragma unroll
            for (int jj = 0; jj < 8; jj++) pk.us[jj] = f2bf(aacc[half * 8 + jj] * scale);
            *(uint4*)&as_[sw_off(cell, half * 8)] = pk.v;
        }
    }
    __syncthreads();   // single barrier: all staging (borders + interiors) done

    // ---- MFMA compute (verified layout) ----
    int lane = t & 63, wv = t >> 6;
    int g = lane >> 4;
    int m16 = lane & 15;
    int gg = g >> 1;
    int c8 = (g & 1) * 8;

    short8 afr[9];
#pragma unroll
    for (int s = 0; s < 9; s++)
        afr[s] = *(const short8*)&w2[m16 * 288 + s * 32 + g * 8];

    const unsigned short* bas[9];
    int tapc[9];
#pragma unroll
    for (int s = 0; s < 9; s++) {
        int kt = 2 * s + gg;
        bas[s] = (kt < 9) ? xs : as_;
        int tap = (kt < 9) ? kt : kt - 9;
        tapc[s] = (tap / 3) * 18 + tap % 3;
    }

    f32x4 binit;
#pragma unroll
    for (int r = 0; r < 4; r++) binit[r] = Wb[g * 4 + r] + Bb[g * 4 + r];

    float* on = out + (size_t)n * NODE_ELEMS;

#pragma unroll
    for (int tt = 0; tt < 4; tt++) {
        int T = wv * 4 + tt;
        int rowc = T * 18 + m16;
        f32x4 a = binit;
#pragma unroll
        for (int s = 0; s < 9; s++) {
            int cl = tapc[s] + rowc;
            short8 bfr = *(const short8*)(bas[s] + sw_off(cl, c8));
            a = __builtin_amdgcn_mfma_f32_16x16x32_bf16(afr[s], bfr, a, 0, 0, 0);
        }
#pragma unroll
        for (int r = 0; r < 4; r++) {
            float v = a[r];
            __builtin_nontemporal_store(v > 0.f ? v : 0.f,
                                        &on[(g * 4 + r) * HW + T * 16 + m16]);
        }
    }
}

// ================= path B: f32 gather fallback (swizzle-matched) =================
__global__ __launch_bounds__(256) void fused_f32(
    const float* __restrict__ x,
    const unsigned short* __restrict__ w2,
    const float* __restrict__ Wb, const float* __restrict__ Bb,
    const int* __restrict__ cnt, const int* __restrict__ esrc2,
    float* __restrict__ out)
{
    __shared__ __align__(16) unsigned short xs[TILE_E];
    __shared__ __align__(16) unsigned short as_[TILE_E];

    int n = blockIdx.x;
    int t = threadIdx.x;
    int h = t >> 4, w = t & 15;

    {
        uint4 z = make_uint4(0, 0, 0, 0);
        uint4* p0 = (uint4*)xs;
        uint4* p1 = (uint4*)as_;
        for (int i = t; i < TILE_E / 8; i += 256) { p0[i] = z; p1[i] = z; }
    }

    const float* xn = x + (size_t)n * NODE_ELEMS;
    int dg = cnt[n];
    int m = dg < CAP ? dg : CAP;
    const int* sl = esrc2 + n * CAP;

    float aacc[16];
#pragma unroll
    for (int k = 0; k < 16; k++) aacc[k] = 0.f;
    for (int j = 0; j < m; j++) {
        const float* xsrc = x + (size_t)sl[j] * NODE_ELEMS;
#pragma unroll
        for (int k = 0; k < 16; k++) aacc[k] += xsrc[k * HW + t];
    }
    float scale = 1.0f / (float)(dg > 1 ? dg : 1);

    __syncthreads();

    {
        int cell = (h + 1) * 18 + (w + 1);
        union { unsigned short us[8]; uint4 v; } pk;
#pragma unroll
        for (int half = 0; half < 2; half++) {
#pragma unroll
            for (int jj = 0; jj < 8; jj++) pk.us[jj] = f2bf(xn[(half * 8 + jj) * HW + t]);
            *(uint4*)&xs[sw_off(cell, half * 8)] = pk.v;
        }
#pragma unroll
        for (int half = 0; half < 2; half++) {
#pragma unroll
            for (int jj = 0; jj < 8; jj++) pk.us[jj] = f2bf(aacc[half * 8 + jj] * scale);
            *(uint4*)&as_[sw_off(cell, half * 8)] = pk.v;
        }
    }
    __syncthreads();

    int lane = t & 63, wv = t >> 6;
    int g = lane >> 4;
    int m16 = lane & 15;
    int gg = g >> 1;
    int c8 = (g & 1) * 8;

    short8 afr[9];
#pragma unroll
    for (int s = 0; s < 9; s++)
        afr[s] = *(const short8*)&w2[m16 * 288 + s * 32 + g * 8];

    const unsigned short* bas[9];
    int tapc[9];
#pragma unroll
    for (int s = 0; s < 9; s++) {
        int kt = 2 * s + gg;
        bas[s] = (kt < 9) ? xs : as_;
        int tap = (kt < 9) ? kt : kt - 9;
        tapc[s] = (tap / 3) * 18 + tap % 3;
    }

    f32x4 binit;
#pragma unroll
    for (int r = 0; r < 4; r++) binit[r] = Wb[g * 4 + r] + Bb[g * 4 + r];

    float* on = out + (size_t)n * NODE_ELEMS;

#pragma unroll
    for (int tt = 0; tt < 4; tt++) {
        int T = wv * 4 + tt;
        int rowc = T * 18 + m16;
        f32x4 a = binit;
#pragma unroll
        for (int s = 0; s < 9; s++) {
            int cl = tapc[s] + rowc;
            short8 bfr = *(const short8*)(bas[s] + sw_off(cl, c8));
            a = __builtin_amdgcn_mfma_f32_16x16x32_bf16(afr[s], bfr, a, 0, 0, 0);
        }
#pragma unroll
        for (int r = 0; r < 4; r++) {
            float v = a[r];
            on[(g * 4 + r) * HW + T * 16 + m16] = v > 0.f ? v : 0.f;
        }
    }
}

extern "C" void kernel_launch(void* const* d_in, const int* in_sizes, int n_in,
                              void* d_out, int out_size, void* d_ws, size_t ws_size,
                              hipStream_t stream) {
    const float* x  = (const float*)d_in[0];
    const int*   ei = (const int*)d_in[1];
    const float* Ww = (const float*)d_in[2];
    const float* Wb = (const float*)d_in[3];
    const float* Bw = (const float*)d_in[4];
    const float* Bb = (const float*)d_in[5];
    float* out = (float*)d_out;

    // ws layout (16B-aligned sections)
    int* cnt   = (int*)d_ws;                                   // 4096 ints
    int* esrc2 = cnt + N_NODES;                                // 4096*CAP ints (512 KiB)
    unsigned short* w2  = (unsigned short*)(esrc2 + N_NODES * CAP);  // 4608 bf16
    unsigned short* xbf = w2 + 4608;                           // 16.7M bf16 (32 MiB)
    size_t need = (size_t)((char*)(xbf + (size_t)N_NODES * NODE_ELEMS) - (char*)d_ws);
    bool bigws = ws_size >= need;

    zero_w2<<<4, 256, 0, stream>>>(cnt, Ww, Bw, w2);
    if (bigws) {
        convert_bucket<<<N_NODES, 256, 0, stream>>>(x, ei, xbf, cnt, esrc2);
        fused_bf<<<N_NODES, 256, 0, stream>>>(xbf, w2, Wb, Bb, cnt, esrc2, out);
    } else {
        bucket_only<<<E_EDGES / 256, 256, 0, stream>>>(ei, cnt, esrc2);
        fused_f32<<<N_NODES, 256, 0, stream>>>(x, w2, Wb, Bb, cnt, esrc2, out);
    }
}

// Round 16
// 61.145 us; speedup vs baseline: 1.0869x; 1.0869x over previous
//
#include <hip/hip_runtime.h>

#define N_NODES 4096
#define HW 256
#define NODE_ELEMS 4096
#define E_EDGES 16384
#define PITCH 16            // 32B cells; halves swizzled (see sw_off) to avoid 4-way banks
#define TILE_E (18*18*PITCH)
#define CAP 32              // per-node edge bucket capacity (deg ~ Poisson(4))

typedef __attribute__((ext_vector_type(8))) short short8;
typedef __attribute__((ext_vector_type(4))) float f32x4;

// swizzled element offset of the 16B half (c8 = 0 or 8) of cell
__device__ inline int sw_off(int cell, int c8) {
    return (cell << 4) + (c8 ^ ((cell & 4) << 1));
}

__device__ inline unsigned short f2bf(float f) {
    union { float f; unsigned int u; } a; a.f = f;
    unsigned int r = a.u + 0x7fffu + ((a.u >> 16) & 1u);   // RNE
    return (unsigned short)(r >> 16);
}

__device__ inline void acc8(float* aacc, uint4 a, uint4 b) {
    unsigned int wd[8] = { a.x, a.y, a.z, a.w, b.x, b.y, b.z, b.w };
#pragma unroll
    for (int m = 0; m < 8; m++) {
        union { unsigned int u; float f; } lo, hi;
        lo.u = wd[m] << 16;
        hi.u = wd[m] & 0xffff0000u;
        aacc[2 * m]     += lo.f;
        aacc[2 * m + 1] += hi.f;
    }
}

// ---- edge-index dtype hedge (int64 vs int32) ----
__device__ inline bool detect_i64(const int* p) {
    int z = 0;
#pragma unroll
    for (int i = 0; i < 16; i++) z += (p[2 * i + 1] == 0) ? 1 : 0;
    return z == 16;
}
__device__ inline int eidx(const int* p, bool i64, int i) { return i64 ? p[2 * i] : p[i]; }

// ---- w2 repack: w2[co*288 + k], k = partSel*144 + tap*16 + c ----
__device__ inline void w2_repack(int t, const float* Ww, const float* Bw,
                                 unsigned short* w2) {
    for (int i = t; i < 16 * 288; i += 256) {
        int co = i / 288, k = i % 288;
        int p = (k >= 144) ? 1 : 0;
        int kk = k - p * 144;
        int tap = kk >> 4, c = kk & 15;
        const float* srcw = p ? Bw : Ww;
        w2[i] = f2bf(srcw[co * 144 + c * 9 + tap]);
    }
}

// 4 blocks: zero cnt (1024 int4) + block 0 repacks weights.
__global__ __launch_bounds__(256) void zero_w2(
    int* __restrict__ cnt,
    const float* __restrict__ Ww, const float* __restrict__ Bw,
    unsigned short* __restrict__ w2)
{
    int t = blockIdx.x * blockDim.x + threadIdx.x;
    ((int4*)cnt)[t] = make_int4(0, 0, 0, 0);
    if (blockIdx.x == 0) w2_repack(threadIdx.x, Ww, Bw, w2);
}

// 4096 blocks: convert node n (f32 [c][pos] -> bf16 [pos][c]) + bucket 4 edges.
__global__ __launch_bounds__(256) void convert_bucket(
    const float* __restrict__ x, const int* __restrict__ ei,
    unsigned short* __restrict__ xbf, int* __restrict__ cnt,
    int* __restrict__ esrc2)
{
    int n = blockIdx.x, t = threadIdx.x;
    if (t < 4) {
        bool i64 = detect_i64(ei);
        int e = n * 4 + t;
        int s = eidx(ei, i64, e);
        int d = eidx(ei, i64, E_EDGES + e);
        int slot = atomicAdd(&cnt[d], 1);
        if (slot < CAP) esrc2[d * CAP + slot] = s;
    }

    const float* xn = x + (size_t)n * NODE_ELEMS;
    union { unsigned int w[4]; uint4 v; } u0, u1;
#pragma unroll
    for (int k2 = 0; k2 < 4; k2++) {
        float a = xn[(2 * k2) * HW + t];
        float b = xn[(2 * k2 + 1) * HW + t];
        u0.w[k2] = (unsigned int)f2bf(a) | ((unsigned int)f2bf(b) << 16);
    }
#pragma unroll
    for (int k2 = 0; k2 < 4; k2++) {
        float a = xn[(8 + 2 * k2) * HW + t];
        float b = xn[(9 + 2 * k2) * HW + t];
        u1.w[k2] = (unsigned int)f2bf(a) | ((unsigned int)f2bf(b) << 16);
    }
    uint4* dst = (uint4*)(xbf + (size_t)n * NODE_ELEMS + t * 16);
    dst[0] = u0.v; dst[1] = u1.v;
}

// Path-B prep: buckets only (no xbf space).
__global__ void bucket_only(const int* __restrict__ ei, int* __restrict__ cnt,
                            int* __restrict__ esrc2) {
    bool i64 = detect_i64(ei);
    int e = blockIdx.x * blockDim.x + threadIdx.x;
    if (e < E_EDGES) {
        int s = eidx(ei, i64, e);
        int d = eidx(ei, i64, E_EDGES + e);
        int slot = atomicAdd(&cnt[d], 1);
        if (slot < CAP) esrc2[d * CAP + slot] = s;
    }
}

// ================= path A: bf16 gather, small swizzled LDS, 1 barrier =================
__global__ __launch_bounds__(256) void fused_bf(
    const unsigned short* __restrict__ xbf,
    const unsigned short* __restrict__ w2,
    const float* __restrict__ Wb, const float* __restrict__ Bb,
    const int* __restrict__ cnt, const int* __restrict__ esrc2,
    float* __restrict__ out)
{
    __shared__ __align__(16) unsigned short xs[TILE_E];
    __shared__ __align__(16) unsigned short as_[TILE_E];

    int n = blockIdx.x;
    int t = threadIdx.x;
    int h = t >> 4, w = t & 15;

    // ---- issue all independent loads up front ----
    int dg = cnt[n];
    const int* sl = esrc2 + n * CAP;
    int4 s03 = *(const int4*)sl;          // unconditional: region always allocated
    int4 s47 = *(const int4*)(sl + 4);
    const uint4* px = (const uint4*)(xbf + (size_t)n * NODE_ELEMS + t * 16);
    uint4 own0 = px[0], own1 = px[1];

    // ---- zero ONLY border cells (interior fully overwritten) ----
    if (t < 136) {
        unsigned short* tile = (t < 68) ? xs : as_;
        int i = (t < 68) ? t : t - 68;
        int r, c;
        if (i < 18)      { r = 0;          c = i; }
        else if (i < 36) { r = 17;         c = i - 18; }
        else if (i < 52) { r = i - 36 + 1; c = 0; }
        else             { r = i - 52 + 1; c = 17; }
        uint4 z = make_uint4(0, 0, 0, 0);
        unsigned short* p = tile + ((r * 18 + c) << 4);
        *(uint4*)p = z; *(uint4*)(p + 8) = z;
    }

    int cell = (h + 1) * 18 + (w + 1);
    // stage own x-tile (swizzled halves)
    *(uint4*)&xs[sw_off(cell, 0)] = own0;
    *(uint4*)&xs[sw_off(cell, 8)] = own1;

    // ---- gather-sum neighbors: guarded quads (uniform branches) ----
    int m = dg < CAP ? dg : CAP;
#define IMG(s) ((const uint4*)(xbf + (size_t)(s) * NODE_ELEMS + t * 16))
    float aacc[16];
#pragma unroll
    for (int k = 0; k < 16; k++) aacc[k] = 0.f;
    {
        uint4 a0, b0, a1, b1, a2, b2, a3, b3;
        if (m > 0) { const uint4* q = IMG(s03.x); a0 = q[0]; b0 = q[1]; }
        if (m > 1) { const uint4* q = IMG(s03.y); a1 = q[0]; b1 = q[1]; }
        if (m > 2) { const uint4* q = IMG(s03.z); a2 = q[0]; b2 = q[1]; }
        if (m > 3) { const uint4* q = IMG(s03.w); a3 = q[0]; b3 = q[1]; }
        if (m > 0) acc8(aacc, a0, b0);
        if (m > 1) acc8(aacc, a1, b1);
        if (m > 2) acc8(aacc, a2, b2);
        if (m > 3) acc8(aacc, a3, b3);
    }
    if (m > 4) {
        uint4 a0, b0, a1, b1, a2, b2, a3, b3;
        { const uint4* q = IMG(s47.x); a0 = q[0]; b0 = q[1]; }
        if (m > 5) { const uint4* q = IMG(s47.y); a1 = q[0]; b1 = q[1]; }
        if (m > 6) { const uint4* q = IMG(s47.z); a2 = q[0]; b2 = q[1]; }
        if (m > 7) { const uint4* q = IMG(s47.w); a3 = q[0]; b3 = q[1]; }
        acc8(aacc, a0, b0);
        if (m > 5) acc8(aacc, a1, b1);
        if (m > 6) acc8(aacc, a2, b2);
        if (m > 7) acc8(aacc, a3, b3);
        for (int j = 8; j < m; j++) { const uint4* q = IMG(sl[j]); acc8(aacc, q[0], q[1]); }
    }
#undef IMG
    float scale = 1.0f / (float)(dg > 1 ? dg : 1);

    {   // stage agg interior (bf16 pack, swizzled halves)
        union { unsigned short us[8]; uint4 v; } pk;
#pragma unroll
        for (int half = 0; half < 2; half++) {
#pragma unroll
            for (int jj = 0; jj < 8; jj++) pk.us[jj] = f2bf(aacc[half * 8 + jj] * scale);
            *(uint4*)&as_[sw_off(cell, half * 8)] = pk.v;
        }
    }
    __syncthreads();   // single barrier: all staging (borders + interiors) done

    // ---- MFMA compute (verified layout) ----
    int lane = t & 63, wv = t >> 6;
    int g = lane >> 4;
    int m16 = lane & 15;
    int gg = g >> 1;
    int c8 = (g & 1) * 8;

    short8 afr[9];
#pragma unroll
    for (int s = 0; s < 9; s++)
        afr[s] = *(const short8*)&w2[m16 * 288 + s * 32 + g * 8];

    const unsigned short* bas[9];
    int tapc[9];
#pragma unroll
    for (int s = 0; s < 9; s++) {
        int kt = 2 * s + gg;
        bas[s] = (kt < 9) ? xs : as_;
        int tap = (kt < 9) ? kt : kt - 9;
        tapc[s] = (tap / 3) * 18 + tap % 3;
    }

    f32x4 binit;
#pragma unroll
    for (int r = 0; r < 4; r++) binit[r] = Wb[g * 4 + r] + Bb[g * 4 + r];

    float* on = out + (size_t)n * NODE_ELEMS;

#pragma unroll
    for (int tt = 0; tt < 4; tt++) {
        int T = wv * 4 + tt;
        int rowc = T * 18 + m16;
        f32x4 a = binit;
#pragma unroll
        for (int s = 0; s < 9; s++) {
            int cl = tapc[s] + rowc;
            short8 bfr = *(const short8*)(bas[s] + sw_off(cl, c8));
            a = __builtin_amdgcn_mfma_f32_16x16x32_bf16(afr[s], bfr, a, 0, 0, 0);
        }
#pragma unroll
        for (int r = 0; r < 4; r++) {
            float v = a[r];
            on[(g * 4 + r) * HW + T * 16 + m16] = v > 0.f ? v : 0.f;
        }
    }
}

// ================= path B: f32 gather fallback (swizzle-matched) =================
__global__ __launch_bounds__(256) void fused_f32(
    const float* __restrict__ x,
    const unsigned short* __restrict__ w2,
    const float* __restrict__ Wb, const float* __restrict__ Bb,
    const int* __restrict__ cnt, const int* __restrict__ esrc2,
    float* __restrict__ out)
{
    __shared__ __align__(16) unsigned short xs[TILE_E];
    __shared__ __align__(16) unsigned short as_[TILE_E];

    int n = blockIdx.x;
    int t = threadIdx.x;
    int h = t >> 4, w = t & 15;

    {
        uint4 z = make_uint4(0, 0, 0, 0);
        uint4* p0 = (uint4*)xs;
        uint4* p1 = (uint4*)as_;
        for (int i = t; i < TILE_E / 8; i += 256) { p0[i] = z; p1[i] = z; }
    }

    const float* xn = x + (size_t)n * NODE_ELEMS;
    int dg = cnt[n];
    int m = dg < CAP ? dg : CAP;
    const int* sl = esrc2 + n * CAP;

    float aacc[16];
#pragma unroll
    for (int k = 0; k < 16; k++) aacc[k] = 0.f;
    for (int j = 0; j < m; j++) {
        const float* xsrc = x + (size_t)sl[j] * NODE_ELEMS;
#pragma unroll
        for (int k = 0; k < 16; k++) aacc[k] += xsrc[k * HW + t];
    }
    float scale = 1.0f / (float)(dg > 1 ? dg : 1);

    __syncthreads();

    {
        int cell = (h + 1) * 18 + (w + 1);
        union { unsigned short us[8]; uint4 v; } pk;
#pragma unroll
        for (int half = 0; half < 2; half++) {
#pragma unroll
            for (int jj = 0; jj < 8; jj++) pk.us[jj] = f2bf(xn[(half * 8 + jj) * HW + t]);
            *(uint4*)&xs[sw_off(cell, half * 8)] = pk.v;
        }
#pragma unroll
        for (int half = 0; half < 2; half++) {
#pragma unroll
            for (int jj = 0; jj < 8; jj++) pk.us[jj] = f2bf(aacc[half * 8 + jj] * scale);
            *(uint4*)&as_[sw_off(cell, half * 8)] = pk.v;
        }
    }
    __syncthreads();

    int lane = t & 63, wv = t >> 6;
    int g = lane >> 4;
    int m16 = lane & 15;
    int gg = g >> 1;
    int c8 = (g & 1) * 8;

    short8 afr[9];
#pragma unroll
    for (int s = 0; s < 9; s++)
        afr[s] = *(const short8*)&w2[m16 * 288 + s * 32 + g * 8];

    const unsigned short* bas[9];
    int tapc[9];
#pragma unroll
    for (int s = 0; s < 9; s++) {
        int kt = 2 * s + gg;
        bas[s] = (kt < 9) ? xs : as_;
        int tap = (kt < 9) ? kt : kt - 9;
        tapc[s] = (tap / 3) * 18 + tap % 3;
    }

    f32x4 binit;
#pragma unroll
    for (int r = 0; r < 4; r++) binit[r] = Wb[g * 4 + r] + Bb[g * 4 + r];

    float* on = out + (size_t)n * NODE_ELEMS;

#pragma unroll
    for (int tt = 0; tt < 4; tt++) {
        int T = wv * 4 + tt;
        int rowc = T * 18 + m16;
        f32x4 a = binit;
#pragma unroll
        for (int s = 0; s < 9; s++) {
            int cl = tapc[s] + rowc;
            short8 bfr = *(const short8*)(bas[s] + sw_off(cl, c8));
            a = __builtin_amdgcn_mfma_f32_16x16x32_bf16(afr[s], bfr, a, 0, 0, 0);
        }
#pragma unroll
        for (int r = 0; r < 4; r++) {
            float v = a[r];
            on[(g * 4 + r) * HW + T * 16 + m16] = v > 0.f ? v : 0.f;
        }
    }
}

extern "C" void kernel_launch(void* const* d_in, const int* in_sizes, int n_in,
                              void* d_out, int out_size, void* d_ws, size_t ws_size,
                              hipStream_t stream) {
    const float* x  = (const float*)d_in[0];
    const int*   ei = (const int*)d_in[1];
    const float* Ww = (const float*)d_in[2];
    const float* Wb = (const float*)d_in[3];
    const float* Bw = (const float*)d_in[4];
    const float* Bb = (const float*)d_in[5];
    float* out = (float*)d_out;

    // ws layout (16B-aligned sections)
    int* cnt   = (int*)d_ws;                                   // 4096 ints
    int* esrc2 = cnt + N_NODES;                                // 4096*CAP ints (512 KiB)
    unsigned short* w2  = (unsigned short*)(esrc2 + N_NODES * CAP);  // 4608 bf16
    unsigned short* xbf = w2 + 4608;                           // 16.7M bf16 (32 MiB)
    size_t need = (size_t)((char*)(xbf + (size_t)N_NODES * NODE_ELEMS) - (char*)d_ws);
    bool bigws = ws_size >= need;

    zero_w2<<<4, 256, 0, stream>>>(cnt, Ww, Bw, w2);
    if (bigws) {
        convert_bucket<<<N_NODES, 256, 0, stream>>>(x, ei, xbf, cnt, esrc2);
        fused_bf<<<N_NODES, 256, 0, stream>>>(xbf, w2, Wb, Bb, cnt, esrc2, out);
    } else {
        bucket_only<<<E_EDGES / 256, 256, 0, stream>>>(ei, cnt, esrc2);
        fused_f32<<<N_NODES, 256, 0, stream>>>(x, w2, Wb, Bb, cnt, esrc2, out);
    }
}